// Round 3
// baseline (262.229 us; speedup 1.0000x reference)
//
#include <hip/hip_runtime.h>
#include <math.h>

// RG-LRU: B=4, T=4096, W=1024, H=8, BW=128
#define NB 4
#define NT 4096
#define NW 1024
#define NH 8
#define CHUNK 64
#define NCH 64          // NT / CHUNK

typedef __attribute__((ext_vector_type(8))) short short8;
typedef __attribute__((ext_vector_type(4))) float f32x4;

__device__ __forceinline__ short bf16rne(float f) {
    unsigned u = __float_as_uint(f);
    u += 0x7fffu + ((u >> 16) & 1u);      // round-to-nearest-even
    return (short)(u >> 16);
}
__device__ __forceinline__ float bf16tof(short h) {
    return __uint_as_float(((unsigned)(unsigned short)h) << 16);
}

// ---------------- K0: convert w_in/w_a to frag-major bf16 hi/lo ----------------
// dst index: ((((h*2+g)*4+ks)*8 + ntg)*64 + lane)*8 + jj
//   where i (input dim) = ks*32 + quad*8 + jj, lane = quad*16 + (j&15), ntg = j>>4
__global__ __launch_bounds__(256)
void k0_wfrag(const float* __restrict__ w_in, const float* __restrict__ w_a,
              short* __restrict__ wfH, short* __restrict__ wfL)
{
    int idx = blockIdx.x * 256 + threadIdx.x;   // over 2*8*128*32 = 65536
    int j4 = (idx & 31) * 4;
    int i  = (idx >> 5) & 127;
    int h  = (idx >> 12) & 7;
    int g  = idx >> 15;
    const float* w = g ? w_a : w_in;
    float4 v = *(const float4*)&w[((size_t)h * 128 + i) * 128 + j4];
    const float vf[4] = {v.x, v.y, v.z, v.w};
    const int ks = i >> 5, q = (i >> 3) & 3, jj = i & 7;
    #pragma unroll
    for (int d = 0; d < 4; ++d) {
        int j = j4 + d;
        int lane = q * 16 + (j & 15);
        int ntg = j >> 4;
        size_t dst = ((size_t)(((h * 2 + g) * 4 + ks) * 8 + ntg) * 64 + lane) * 8 + jj;
        short hb = bf16rne(vf[d]);
        wfH[dst] = hb;
        wfL[dst] = bf16rne(vf[d] - bf16tof(hb));
    }
}

// ---------------- K1: MFMA gates + in-register chunk-local scan ----------------
// grid (NH, NB*NCH), block 256 (4 waves). Block tile: 64 t (one chunk) x 128 w (one head).
// 3-pass bf16-split MFMA (xh*wh + xh*wl + xl*wh) for fp32-level logit accuracy.
// All transcendentals + shuffle scans happen BEFORE any barrier (latency overlap);
// barriers only fence the LDS-transpose drain.
__global__ __launch_bounds__(256)
void k1_gates_scan(const float* __restrict__ x, const int* __restrict__ seg,
                   const float* __restrict__ a_param,
                   const float* __restrict__ b_in, const float* __restrict__ b_a,
                   const short* __restrict__ wfH, const short* __restrict__ wfL,
                   unsigned short* __restrict__ Pb, float* __restrict__ out,
                   float* __restrict__ Atop, float* __restrict__ Htop)
{
    __shared__ float sP[16][132];   // pad 132: 2-way (free) bank aliasing
    __shared__ float sH[16][132];

    const int h   = blockIdx.x;
    const int bc  = blockIdx.y;
    const int b   = bc >> 6, c = bc & 63;
    const int tid = threadIdx.x;
    const int wave = tid >> 6, lane = tid & 63;
    const int quad = lane >> 4, m = lane & 15;
    const int row0 = b * NT + c * CHUNK;        // global row into [B*T]
    const int ntg0 = wave * 2;

    f32x4 acc[2][2][4];  // [gate][nt][mt]
    #pragma unroll
    for (int g = 0; g < 2; ++g)
        #pragma unroll
        for (int nt = 0; nt < 2; ++nt)
            #pragma unroll
            for (int mt = 0; mt < 4; ++mt)
                acc[g][nt][mt] = (f32x4){0.f, 0.f, 0.f, 0.f};

    // ---- MFMA main loop over K ----
    #pragma unroll
    for (int ks = 0; ks < 4; ++ks) {
        short8 ah[4], al[4];
        #pragma unroll
        for (int mt = 0; mt < 4; ++mt) {
            const float* px = x + (size_t)(row0 + mt * 16 + m) * NW + h * 128 + ks * 32 + quad * 8;
            float4 u0 = *(const float4*)px;
            float4 u1 = *(const float4*)(px + 4);
            const float uf[8] = {u0.x, u0.y, u0.z, u0.w, u1.x, u1.y, u1.z, u1.w};
            short8 hh, ll;
            #pragma unroll
            for (int j = 0; j < 8; ++j) {
                short hb = bf16rne(uf[j]);
                hh[j] = hb;
                ll[j] = bf16rne(uf[j] - bf16tof(hb));
            }
            ah[mt] = hh; al[mt] = ll;
        }
        #pragma unroll
        for (int g = 0; g < 2; ++g) {
            #pragma unroll
            for (int nt = 0; nt < 2; ++nt) {
                const size_t fo = ((size_t)(((h * 2 + g) * 4 + ks) * 8 + (ntg0 + nt)) * 64 + lane) * 8;
                short8 bh = *(const short8*)(wfH + fo);
                short8 bl = *(const short8*)(wfL + fo);
                #pragma unroll
                for (int mt = 0; mt < 4; ++mt) {
                    acc[g][nt][mt] = __builtin_amdgcn_mfma_f32_16x16x32_bf16(ah[mt], bh, acc[g][nt][mt], 0, 0, 0);
                    acc[g][nt][mt] = __builtin_amdgcn_mfma_f32_16x16x32_bf16(ah[mt], bl, acc[g][nt][mt], 0, 0, 0);
                    acc[g][nt][mt] = __builtin_amdgcn_mfma_f32_16x16x32_bf16(al[mt], bh, acc[g][nt][mt], 0, 0, 0);
                }
            }
        }
    }

    // ---- per-column parameters ----
    float bi[2], ba[2], c2[2];
    #pragma unroll
    for (int nt = 0; nt < 2; ++nt) {
        int colg = h * 128 + (ntg0 + nt) * 16 + m;
        bi[nt] = b_in[colg];
        ba[nt] = b_a[colg];
        c2[nt] = -8.0f * log1pf(expf(a_param[colg]));   // -8*softplus (precise, 2/thread)
    }

    // ======== Phase A: transcendentals + lane-local scans (no barriers) ========
    // C layout: row = quad*4+reg, col = lane&15.  t(within chunk) = mt*16 + quad*4 + r
    float lP[2][4][4], lH[2][4][4];
    #pragma unroll
    for (int nt = 0; nt < 2; ++nt) {
        const int colg = h * 128 + (ntg0 + nt) * 16 + m;
        #pragma unroll
        for (int mt = 0; mt < 4; ++mt) {
            float xv[4]; int sv[4];
            #pragma unroll
            for (int r = 0; r < 4; ++r) {
                const int rowi = row0 + mt * 16 + quad * 4 + r;
                xv[r] = x[(size_t)rowi * NW + colg];
                sv[r] = seg[rowi];
            }
            #pragma unroll
            for (int r = 0; r < 4; ++r) {
                const float zx = acc[0][nt][mt][r] + bi[nt];
                const float za = acc[1][nt][mt][r] + ba[nt];
                const float gx = __fdividef(1.f, 1.f + __expf(-zx));
                const float ga = __fdividef(1.f, 1.f + __expf(-za));
                const float a  = __expf(c2[nt] * ga);
                const float mult = sqrtf(fmaxf(fmaf(-a, a, 1.f), 0.f));
                const float av = (sv[r] == 0) ? 0.f : a;
                const float nx = xv[r] * gx * mult;
                lP[nt][mt][r] = (r == 0) ? av : lP[nt][mt][r - 1] * av;
                lH[nt][mt][r] = (r == 0) ? nx : fmaf(av, lH[nt][mt][r - 1], nx);
            }
        }
    }

    // ======== Phase B: 8 independent cross-quad scans (shuffle latencies overlap) ========
    float eA[2][4], eH[2][4], mA[2][4], mH[2][4];
    #pragma unroll
    for (int nt = 0; nt < 2; ++nt) {
        #pragma unroll
        for (int mt = 0; mt < 4; ++mt) {
            float iA = lP[nt][mt][3], iH = lH[nt][mt][3];
            float uA = __shfl_up(iA, 16), uH = __shfl_up(iH, 16);
            if (quad >= 1) { iH = fmaf(iA, uH, iH); iA = uA * iA; }
            uA = __shfl_up(iA, 32); uH = __shfl_up(iH, 32);
            if (quad >= 2) { iH = fmaf(iA, uH, iH); iA = uA * iA; }
            float xA = __shfl_up(iA, 16), xH = __shfl_up(iH, 16);
            eA[nt][mt] = (quad == 0) ? 1.f : xA;
            eH[nt][mt] = (quad == 0) ? 0.f : xH;
            mA[nt][mt] = __shfl(iA, 48 + m);   // 16-t tile total (quad3 inclusive)
            mH[nt][mt] = __shfl(iH, 48 + m);
        }
    }

    // ======== Phase C: register-only carry across mt ========
    float pA[2][4], pH[2][4];
    #pragma unroll
    for (int nt = 0; nt < 2; ++nt) {
        float cA = 1.f, cH = 0.f;
        #pragma unroll
        for (int mt = 0; mt < 4; ++mt) {
            pA[nt][mt] = cA * eA[nt][mt];
            pH[nt][mt] = fmaf(eA[nt][mt], cH, eH[nt][mt]);
            cH = fmaf(mA[nt][mt], cH, mH[nt][mt]);
            cA = cA * mA[nt][mt];
        }
    }

    // ======== Phase D: per-mt LDS transpose + coalesced drain ========
    for (int mt = 0; mt < 4; ++mt) {
        #pragma unroll
        for (int nt = 0; nt < 2; ++nt) {
            const int colw = (ntg0 + nt) * 16 + m;
            #pragma unroll
            for (int r = 0; r < 4; ++r) {
                const float Pf = pA[nt][mt] * lP[nt][mt][r];
                const float Hf = fmaf(lP[nt][mt][r], pH[nt][mt], lH[nt][mt][r]);
                sP[quad * 4 + r][colw] = Pf;
                sH[quad * 4 + r][colw] = Hf;
            }
        }
        __syncthreads();
        #pragma unroll
        for (int pass = 0; pass < 2; ++pass) {
            const int row = pass * 8 + (tid >> 5);
            const int c4  = tid & 31;
            float4 vP = *(float4*)&sP[row][c4 * 4];
            float4 vH = *(float4*)&sH[row][c4 * 4];
            ushort4 pb;
            pb.x = (unsigned short)bf16rne(vP.x);
            pb.y = (unsigned short)bf16rne(vP.y);
            pb.z = (unsigned short)bf16rne(vP.z);
            pb.w = (unsigned short)bf16rne(vP.w);
            const size_t go = (size_t)(row0 + mt * 16 + row) * NW + h * 128 + c4 * 4;
            *(ushort4*)&Pb[go] = pb;
            *(float4*)&out[go] = vH;
            if (mt == 3 && row == 15) {   // chunk tops (fp32) for inter-chunk scan
                const size_t to = (size_t)bc * NW + h * 128 + c4 * 4;
                *(float4*)&Atop[to] = vP;
                *(float4*)&Htop[to] = vH;
            }
        }
        __syncthreads();
    }
}

// ---------------- K3: inter-chunk exclusive scan (separate out buffer -> hoistable loads) ----------------
__global__ __launch_bounds__(256)
void k3_tops(const float* __restrict__ Atop, const float* __restrict__ Htop,
             float* __restrict__ Hst)
{
    const int idx = blockIdx.x * 256 + threadIdx.x;   // over NB*NW
    const int w = idx & (NW - 1);
    const int b = idx >> 10;
    const size_t base = (size_t)b * NCH * NW + w;
    float hh = 0.f;
    #pragma unroll
    for (int cc = 0; cc < NCH; ++cc) {
        const size_t o = base + (size_t)cc * NW;
        Hst[o] = hh;                 // exclusive: state entering chunk cc
        hh = fmaf(Atop[o], hh, Htop[o]);
    }
}

// ---------------- K4: elementwise fix-up  out = localh + P * h_start ----------------
__global__ __launch_bounds__(256)
void k4_apply(const unsigned short* __restrict__ Pb, const float* __restrict__ Hst,
              float* __restrict__ out)
{
    const int idx = blockIdx.x * 256 + threadIdx.x;   // over NB*NT*NW/4
    const int row = idx >> 8;                          // b*NT + t
    const int w4  = (idx & 255) * 4;
    const int c = (row & (NT - 1)) >> 6;
    const int b = row >> 12;
    const size_t go = (size_t)row * NW + w4;
    ushort4 pv = *(const ushort4*)&Pb[go];
    float4 lh = *(const float4*)&out[go];
    float4 hs = *(const float4*)&Hst[((size_t)(b * NCH + c)) * NW + w4];
    float4 o;
    o.x = fmaf(bf16tof((short)pv.x), hs.x, lh.x);
    o.y = fmaf(bf16tof((short)pv.y), hs.y, lh.y);
    o.z = fmaf(bf16tof((short)pv.z), hs.z, lh.z);
    o.w = fmaf(bf16tof((short)pv.w), hs.w, lh.w);
    *(float4*)&out[go] = o;
}

extern "C" void kernel_launch(void* const* d_in, const int* in_sizes, int n_in,
                              void* d_out, int out_size, void* d_ws, size_t ws_size,
                              hipStream_t stream)
{
    (void)in_sizes; (void)n_in; (void)out_size; (void)ws_size;
    const float* x    = (const float*)d_in[0];
    const int*   seg  = (const int*)  d_in[1];
    const float* ap   = (const float*)d_in[2];
    const float* w_in = (const float*)d_in[3];
    const float* b_in = (const float*)d_in[4];
    const float* w_a  = (const float*)d_in[5];
    const float* b_a  = (const float*)d_in[6];
    float* out = (float*)d_out;

    // ws layout (~37 MiB, well under the 67 MiB footprint already validated):
    //   Pb    : NB*NT*NW bf16          = 32 MiB
    //   Atop/Htop/Hst : NB*NCH*NW fp32 =  1 MiB each
    //   wfH/L : 2*8*128*128 bf16 each  =  1 MiB
    unsigned short* Pb = (unsigned short*)d_ws;
    float* Atop = (float*)(Pb + (size_t)NB * NT * NW);
    float* Htop = Atop + (size_t)NB * NCH * NW;
    float* Hst  = Htop + (size_t)NB * NCH * NW;
    short* wfH  = (short*)(Hst + (size_t)NB * NCH * NW);
    short* wfL  = wfH + (size_t)2 * NH * 128 * 128;

    k0_wfrag<<<256, 256, 0, stream>>>(w_in, w_a, wfH, wfL);
    dim3 g1(NH, NB * NCH);
    k1_gates_scan<<<g1, 256, 0, stream>>>(x, seg, ap, b_in, b_a, wfH, wfL,
                                          Pb, out, Atop, Htop);
    k3_tops<<<(NB * NW) / 256, 256, 0, stream>>>(Atop, Htop, Hst);
    k4_apply<<<((size_t)NB * NT * NW / 4) / 256, 256, 0, stream>>>(Pb, Hst, out);
}

// Round 4
// 221.571 us; speedup vs baseline: 1.1835x; 1.1835x over previous
//
#include <hip/hip_runtime.h>
#include <math.h>

// RG-LRU: B=4, T=4096, W=1024, H=8, BW=128
#define NB 4
#define NT 4096
#define NW 1024
#define NH 8
#define CHUNK 64
#define NCH 64          // NT / CHUNK

typedef __attribute__((ext_vector_type(8))) short short8;
typedef __attribute__((ext_vector_type(4))) float f32x4;

__device__ __forceinline__ short bf16rne(float f) {
    unsigned u = __float_as_uint(f);
    u += 0x7fffu + ((u >> 16) & 1u);      // round-to-nearest-even
    return (short)(u >> 16);
}
__device__ __forceinline__ float bf16tof(short h) {
    return __uint_as_float(((unsigned)(unsigned short)h) << 16);
}

// ---------------- K0: convert w_in/w_a to frag-major bf16 ----------------
// dst index: ((((h*2+g)*4+ks)*8 + ntg)*64 + lane)*8 + jj
//   where i (input dim) = ks*32 + quad*8 + jj, lane = quad*16 + (j&15), ntg = j>>4
__global__ __launch_bounds__(256)
void k0_wfrag(const float* __restrict__ w_in, const float* __restrict__ w_a,
              short* __restrict__ wfH)
{
    int idx = blockIdx.x * 256 + threadIdx.x;   // over 2*8*128*32 = 65536
    int j4 = (idx & 31) * 4;
    int i  = (idx >> 5) & 127;
    int h  = (idx >> 12) & 7;
    int g  = idx >> 15;
    const float* w = g ? w_a : w_in;
    float4 v = *(const float4*)&w[((size_t)h * 128 + i) * 128 + j4];
    const float vf[4] = {v.x, v.y, v.z, v.w};
    const int ks = i >> 5, q = (i >> 3) & 3, jj = i & 7;
    #pragma unroll
    for (int d = 0; d < 4; ++d) {
        int j = j4 + d;
        int lane = q * 16 + (j & 15);
        int ntg = j >> 4;
        size_t dst = ((size_t)(((h * 2 + g) * 4 + ks) * 8 + ntg) * 64 + lane) * 8 + jj;
        wfH[dst] = bf16rne(vf[d]);
    }
}

// ---------------- K1: MFMA gates + in-register chunk-local scan ----------------
// grid (NH, NB*NCH), block 512 (8 waves). Block tile: 64 t (one chunk) x 128 w (one head).
// Each wave owns ONE 16-col n-tile -> acc = 32 VGPRs/thread (2 gates x 4 mt x 4).
// Single-pass bf16 MFMA (error self-regularized through the decay path).
// Interleaved per-mt epilogue keeps scan-state live ranges short (occupancy!).
__global__ __launch_bounds__(512)
void k1_gates_scan(const float* __restrict__ x, const int* __restrict__ seg,
                   const float* __restrict__ a_param,
                   const float* __restrict__ b_in, const float* __restrict__ b_a,
                   const short* __restrict__ wfH,
                   unsigned short* __restrict__ Pb, float* __restrict__ out,
                   float* __restrict__ Atop, float* __restrict__ Htop)
{
    __shared__ float sP[16][132];   // pad 132: 2-way (free) bank aliasing
    __shared__ float sH[16][132];

    const int h   = blockIdx.x;
    const int bc  = blockIdx.y;
    const int b   = bc >> 6, c = bc & 63;
    const int tid = threadIdx.x;
    const int wave = tid >> 6, lane = tid & 63;   // wave = ntg (0..7)
    const int quad = lane >> 4, m = lane & 15;
    const int row0 = b * NT + c * CHUNK;          // global row into [B*T]

    f32x4 acc[2][4];  // [gate][mt]
    #pragma unroll
    for (int g = 0; g < 2; ++g)
        #pragma unroll
        for (int mt = 0; mt < 4; ++mt)
            acc[g][mt] = (f32x4){0.f, 0.f, 0.f, 0.f};

    // ---- MFMA main loop over K ----
    #pragma unroll
    for (int ks = 0; ks < 4; ++ks) {
        short8 ah[4];
        #pragma unroll
        for (int mt = 0; mt < 4; ++mt) {
            const float* px = x + (size_t)(row0 + mt * 16 + m) * NW + h * 128 + ks * 32 + quad * 8;
            float4 u0 = *(const float4*)px;
            float4 u1 = *(const float4*)(px + 4);
            const float uf[8] = {u0.x, u0.y, u0.z, u0.w, u1.x, u1.y, u1.z, u1.w};
            short8 hh;
            #pragma unroll
            for (int j = 0; j < 8; ++j) hh[j] = bf16rne(uf[j]);
            ah[mt] = hh;
        }
        #pragma unroll
        for (int g = 0; g < 2; ++g) {
            const size_t fo = ((size_t)(((h * 2 + g) * 4 + ks) * 8 + wave) * 64 + lane) * 8;
            short8 bh = *(const short8*)(wfH + fo);
            #pragma unroll
            for (int mt = 0; mt < 4; ++mt)
                acc[g][mt] = __builtin_amdgcn_mfma_f32_16x16x32_bf16(ah[mt], bh, acc[g][mt], 0, 0, 0);
        }
    }

    // ---- per-column parameters ----
    const int colg = h * 128 + wave * 16 + m;
    const float bi = b_in[colg];
    const float ba = b_a[colg];
    const float c2 = -8.0f * log1pf(expf(a_param[colg]));   // -8*softplus (precise, 1/thread)

    // ---- interleaved epilogue + scan (C layout: row = quad*4+reg, col = lane&15) ----
    float cA = 1.f, cH = 0.f;   // carry across m-tiles (per column)
    for (int mt = 0; mt < 4; ++mt) {
        float lP[4], lH[4];
        {
            float xv[4]; int sv[4];
            #pragma unroll
            for (int r = 0; r < 4; ++r) {
                const int rowi = row0 + mt * 16 + quad * 4 + r;
                xv[r] = x[(size_t)rowi * NW + colg];
                sv[r] = seg[rowi];
            }
            #pragma unroll
            for (int r = 0; r < 4; ++r) {
                const float zx = acc[0][mt][r] + bi;
                const float za = acc[1][mt][r] + ba;
                const float gx = __fdividef(1.f, 1.f + __expf(-zx));
                const float ga = __fdividef(1.f, 1.f + __expf(-za));
                const float a  = __expf(c2 * ga);
                const float mult = sqrtf(fmaxf(fmaf(-a, a, 1.f), 0.f));
                const float av = (sv[r] == 0) ? 0.f : a;
                const float nx = xv[r] * gx * mult;
                lP[r] = (r == 0) ? av : lP[r - 1] * av;
                lH[r] = (r == 0) ? nx : fmaf(av, lH[r - 1], nx);
            }
        }
        // cross-quad inclusive scan of quad totals
        float iA = lP[3], iH = lH[3];
        float uA = __shfl_up(iA, 16), uH = __shfl_up(iH, 16);
        if (quad >= 1) { iH = fmaf(iA, uH, iH); iA = uA * iA; }
        uA = __shfl_up(iA, 32); uH = __shfl_up(iH, 32);
        if (quad >= 2) { iH = fmaf(iA, uH, iH); iA = uA * iA; }
        // exclusive prefix for this quad
        float eA = __shfl_up(iA, 16), eH = __shfl_up(iH, 16);
        if (quad == 0) { eA = 1.f; eH = 0.f; }
        // 16-t tile total (quad 3 inclusive), broadcast to all quads of this column
        const float mAt = __shfl(iA, 48 + m);
        const float mHt = __shfl(iH, 48 + m);
        // prefix = carry ∘ quad-exclusive; update carry
        const float pA = cA * eA;
        const float pH = fmaf(eA, cH, eH);
        cH = fmaf(mAt, cH, mHt);
        cA = cA * mAt;
        // finals -> LDS (for coalesced transposed store)
        #pragma unroll
        for (int r = 0; r < 4; ++r) {
            sP[quad * 4 + r][colg & 127] = pA * lP[r];
            sH[quad * 4 + r][colg & 127] = fmaf(lP[r], pH, lH[r]);
        }
        __syncthreads();
        // drain: 16 rows x 128 cols, 512 threads -> one float4 per thread per array
        {
            const int row = tid >> 5;
            const int c4  = tid & 31;
            float4 vP = *(float4*)&sP[row][c4 * 4];
            float4 vH = *(float4*)&sH[row][c4 * 4];
            ushort4 pb;
            pb.x = (unsigned short)bf16rne(vP.x);
            pb.y = (unsigned short)bf16rne(vP.y);
            pb.z = (unsigned short)bf16rne(vP.z);
            pb.w = (unsigned short)bf16rne(vP.w);
            const size_t go = (size_t)(row0 + mt * 16 + row) * NW + h * 128 + c4 * 4;
            *(ushort4*)&Pb[go] = pb;
            *(float4*)&out[go] = vH;
            if (mt == 3 && row == 15) {   // chunk tops (fp32) for inter-chunk scan
                const size_t to = (size_t)bc * NW + h * 128 + c4 * 4;
                *(float4*)&Atop[to] = vP;
                *(float4*)&Htop[to] = vH;
            }
        }
        __syncthreads();
    }
}

// ---------------- K3: inter-chunk exclusive scan (separate out buffer -> hoistable loads) ----------------
__global__ __launch_bounds__(256)
void k3_tops(const float* __restrict__ Atop, const float* __restrict__ Htop,
             float* __restrict__ Hst)
{
    const int idx = blockIdx.x * 256 + threadIdx.x;   // over NB*NW
    const int w = idx & (NW - 1);
    const int b = idx >> 10;
    const size_t base = (size_t)b * NCH * NW + w;
    float hh = 0.f;
    #pragma unroll
    for (int cc = 0; cc < NCH; ++cc) {
        const size_t o = base + (size_t)cc * NW;
        Hst[o] = hh;                 // exclusive: state entering chunk cc
        hh = fmaf(Atop[o], hh, Htop[o]);
    }
}

// ---------------- K4: elementwise fix-up  out = localh + P * h_start ----------------
__global__ __launch_bounds__(256)
void k4_apply(const unsigned short* __restrict__ Pb, const float* __restrict__ Hst,
              float* __restrict__ out)
{
    const int idx = blockIdx.x * 256 + threadIdx.x;   // over NB*NT*NW/4
    const int row = idx >> 8;                          // b*NT + t
    const int w4  = (idx & 255) * 4;
    const int c = (row & (NT - 1)) >> 6;
    const int b = row >> 12;
    const size_t go = (size_t)row * NW + w4;
    ushort4 pv = *(const ushort4*)&Pb[go];
    float4 lh = *(const float4*)&out[go];
    float4 hs = *(const float4*)&Hst[((size_t)(b * NCH + c)) * NW + w4];
    float4 o;
    o.x = fmaf(bf16tof((short)pv.x), hs.x, lh.x);
    o.y = fmaf(bf16tof((short)pv.y), hs.y, lh.y);
    o.z = fmaf(bf16tof((short)pv.z), hs.z, lh.z);
    o.w = fmaf(bf16tof((short)pv.w), hs.w, lh.w);
    *(float4*)&out[go] = o;
}

extern "C" void kernel_launch(void* const* d_in, const int* in_sizes, int n_in,
                              void* d_out, int out_size, void* d_ws, size_t ws_size,
                              hipStream_t stream)
{
    (void)in_sizes; (void)n_in; (void)out_size; (void)ws_size;
    const float* x    = (const float*)d_in[0];
    const int*   seg  = (const int*)  d_in[1];
    const float* ap   = (const float*)d_in[2];
    const float* w_in = (const float*)d_in[3];
    const float* b_in = (const float*)d_in[4];
    const float* w_a  = (const float*)d_in[5];
    const float* b_a  = (const float*)d_in[6];
    float* out = (float*)d_out;

    // ws layout (~36 MiB):
    //   Pb    : NB*NT*NW bf16          = 32 MiB
    //   Atop/Htop/Hst : NB*NCH*NW fp32 =  1 MiB each
    //   wfH   : 2*8*128*128 bf16       = 0.5 MiB
    unsigned short* Pb = (unsigned short*)d_ws;
    float* Atop = (float*)(Pb + (size_t)NB * NT * NW);
    float* Htop = Atop + (size_t)NB * NCH * NW;
    float* Hst  = Htop + (size_t)NB * NCH * NW;
    short* wfH  = (short*)(Hst + (size_t)NB * NCH * NW);

    k0_wfrag<<<256, 256, 0, stream>>>(w_in, w_a, wfH);
    dim3 g1(NH, NB * NCH);
    k1_gates_scan<<<g1, 512, 0, stream>>>(x, seg, ap, b_in, b_a, wfH,
                                          Pb, out, Atop, Htop);
    k3_tops<<<(NB * NW) / 256, 256, 0, stream>>>(Atop, Htop, Hst);
    k4_apply<<<((size_t)NB * NT * NW / 4) / 256, 256, 0, stream>>>(Pb, Hst, out);
}

// Round 5
// 188.645 us; speedup vs baseline: 1.3901x; 1.1745x over previous
//
#include <hip/hip_runtime.h>
#include <math.h>

// RG-LRU: B=4, T=4096, W=1024, H=8, BW=128
#define NB 4
#define NT 4096
#define NW 1024
#define NH 8
#define CHUNK 64
#define NCH 64          // NT / CHUNK
#define STRIDE_A 136    // bf16 elems per LDS A-row: 272 B = 17*16 (16B-aligned, bank-friendly)

typedef __attribute__((ext_vector_type(8))) short short8;
typedef __attribute__((ext_vector_type(4))) float f32x4;

__device__ __forceinline__ short bf16rne(float f) {
    unsigned u = __float_as_uint(f);
    u += 0x7fffu + ((u >> 16) & 1u);      // round-to-nearest-even
    return (short)(u >> 16);
}

// ---------------- K0: convert w_in/w_a to frag-major bf16 ----------------
// dst index: ((((h*2+g)*4+ks)*8 + ntg)*64 + lane)*8 + jj
//   where i (input dim) = ks*32 + quad*8 + jj, lane = quad*16 + (j&15), ntg = j>>4
__global__ __launch_bounds__(256)
void k0_wfrag(const float* __restrict__ w_in, const float* __restrict__ w_a,
              short* __restrict__ wfH)
{
    int idx = blockIdx.x * 256 + threadIdx.x;   // over 2*8*128*32 = 65536
    int j4 = (idx & 31) * 4;
    int i  = (idx >> 5) & 127;
    int h  = (idx >> 12) & 7;
    int g  = idx >> 15;
    const float* w = g ? w_a : w_in;
    float4 v = *(const float4*)&w[((size_t)h * 128 + i) * 128 + j4];
    const float vf[4] = {v.x, v.y, v.z, v.w};
    const int ks = i >> 5, q = (i >> 3) & 3, jj = i & 7;
    #pragma unroll
    for (int d = 0; d < 4; ++d) {
        int j = j4 + d;
        int lane = q * 16 + (j & 15);
        int ntg = j >> 4;
        size_t dst = ((size_t)(((h * 2 + g) * 4 + ks) * 8 + ntg) * 64 + lane) * 8 + jj;
        wfH[dst] = bf16rne(vf[d]);
    }
}

// ---------------- K-pass: MFMA gates + chunk-local scan (run twice) ----------------
// grid (NH, NB*NCH), block 512 (8 waves); block tile = 64 t x 128 w (one head).
// pass 1 (final=0): emit per-chunk totals (cA,cH) only.
// pass 2 (final=1): recompute, add P*h_start (from Hst), store out directly.
// x-tile staged ONCE into LDS as bf16 A-frags (ONE barrier; no output transpose).
__global__ __launch_bounds__(512)
void k_pass(const float* __restrict__ x, const int* __restrict__ seg,
            const float* __restrict__ a_param,
            const float* __restrict__ b_in, const float* __restrict__ b_a,
            const short* __restrict__ wfH,
            const float* __restrict__ Hst,      // pass2: chunk-start states
            float* __restrict__ Atop, float* __restrict__ Htop,
            float* __restrict__ out, const int final_pass)
{
    __shared__ short sA[64 * STRIDE_A];   // 17.4 KB

    const int h   = blockIdx.x;
    const int bc  = blockIdx.y;           // b*NCH + c
    const int b   = bc >> 6, c = bc & 63;
    const int tid = threadIdx.x;
    const int wave = tid >> 6, lane = tid & 63;   // wave = n-tile group (0..7)
    const int quad = lane >> 4, m = lane & 15;
    const int row0 = b * NT + c * CHUNK;          // global row into [B*T]

    // ---- stage A: x tile (64 t x 128 k) -> bf16 LDS, one conversion per element ----
    {
        const int r  = tid >> 3;           // 0..63
        const int k0 = (tid & 7) * 16;     // 0,16,..,112
        const float4* px = (const float4*)(x + (size_t)(row0 + r) * NW + h * 128 + k0);
        float4 v0 = px[0], v1 = px[1], v2 = px[2], v3 = px[3];
        const float f[16] = {v0.x, v0.y, v0.z, v0.w, v1.x, v1.y, v1.z, v1.w,
                             v2.x, v2.y, v2.z, v2.w, v3.x, v3.y, v3.z, v3.w};
        short8 s0, s1;
        #pragma unroll
        for (int j = 0; j < 8; ++j) { s0[j] = bf16rne(f[j]); s1[j] = bf16rne(f[8 + j]); }
        *(short8*)&sA[r * STRIDE_A + k0]     = s0;
        *(short8*)&sA[r * STRIDE_A + k0 + 8] = s1;
    }
    __syncthreads();

    // ---- MFMA main loop over K (A from LDS, B frags from L2-resident wfH) ----
    f32x4 acc[2][4];  // [gate][mt]
    #pragma unroll
    for (int g = 0; g < 2; ++g)
        #pragma unroll
        for (int mt = 0; mt < 4; ++mt)
            acc[g][mt] = (f32x4){0.f, 0.f, 0.f, 0.f};

    #pragma unroll
    for (int ks = 0; ks < 4; ++ks) {
        short8 ah[4];
        #pragma unroll
        for (int mt = 0; mt < 4; ++mt)
            ah[mt] = *(const short8*)&sA[(mt * 16 + m) * STRIDE_A + ks * 32 + quad * 8];
        #pragma unroll
        for (int g = 0; g < 2; ++g) {
            const size_t fo = ((size_t)(((h * 2 + g) * 4 + ks) * 8 + wave) * 64 + lane) * 8;
            short8 bh = *(const short8*)(wfH + fo);
            #pragma unroll
            for (int mt = 0; mt < 4; ++mt)
                acc[g][mt] = __builtin_amdgcn_mfma_f32_16x16x32_bf16(ah[mt], bh, acc[g][mt], 0, 0, 0);
        }
    }

    // ---- per-column parameters ----
    const int col  = wave * 16 + m;       // 0..127 within head
    const int colg = h * 128 + col;
    const float bi = b_in[colg];
    const float ba = b_a[colg];
    const float c2 = -8.0f * log1pf(expf(a_param[colg]));   // -8*softplus
    const size_t topbase = ((size_t)(h * NB + b) * NCH + c) * 128;
    const float hprev = final_pass ? Hst[topbase + col] : 0.f;

    // ---- epilogue + scan (C layout: row = quad*4+reg, col = lane&15) ----
    float cA = 1.f, cH = 0.f;   // carry across m-tiles (per column)
    for (int mt = 0; mt < 4; ++mt) {
        float lP[4], lH[4];
        {
            float xv[4]; int sv[4];
            #pragma unroll
            for (int r = 0; r < 4; ++r) {
                const int rowi = row0 + mt * 16 + quad * 4 + r;
                xv[r] = x[(size_t)rowi * NW + colg];
                sv[r] = seg[rowi];
            }
            #pragma unroll
            for (int r = 0; r < 4; ++r) {
                const float zx = acc[0][mt][r] + bi;
                const float za = acc[1][mt][r] + ba;
                const float gx = __fdividef(1.f, 1.f + __expf(-zx));
                const float ga = __fdividef(1.f, 1.f + __expf(-za));
                const float a  = __expf(c2 * ga);
                const float mult = sqrtf(fmaxf(fmaf(-a, a, 1.f), 0.f));
                const float av = (sv[r] == 0) ? 0.f : a;
                const float nx = xv[r] * gx * mult;
                lP[r] = (r == 0) ? av : lP[r - 1] * av;
                lH[r] = (r == 0) ? nx : fmaf(av, lH[r - 1], nx);
            }
        }
        // cross-quad inclusive scan of quad totals
        float iA = lP[3], iH = lH[3];
        float uA = __shfl_up(iA, 16), uH = __shfl_up(iH, 16);
        if (quad >= 1) { iH = fmaf(iA, uH, iH); iA = uA * iA; }
        uA = __shfl_up(iA, 32); uH = __shfl_up(iH, 32);
        if (quad >= 2) { iH = fmaf(iA, uH, iH); iA = uA * iA; }
        // exclusive prefix for this quad
        float eA = __shfl_up(iA, 16), eH = __shfl_up(iH, 16);
        if (quad == 0) { eA = 1.f; eH = 0.f; }
        // 16-t tile total (quad 3 inclusive), broadcast per column
        const float mAt = __shfl(iA, 48 + m);
        const float mHt = __shfl(iH, 48 + m);
        // prefix = carry ∘ quad-exclusive; update carry
        const float pA = cA * eA;
        const float pH = fmaf(eA, cH, eH);
        cH = fmaf(mAt, cH, mHt);
        cA = cA * mAt;
        if (final_pass) {
            // out = localh + P * h_start, stored directly (64B sectors per quad-row)
            #pragma unroll
            for (int r = 0; r < 4; ++r) {
                const int rowi = row0 + mt * 16 + quad * 4 + r;
                const float Pf = pA * lP[r];
                const float Hf = fmaf(lP[r], pH, lH[r]);
                out[(size_t)rowi * NW + colg] = fmaf(Pf, hprev, Hf);
            }
        }
    }
    if (!final_pass && quad == 0) {       // every column's totals live in quad-0 lanes
        Atop[topbase + col] = cA;
        Htop[topbase + col] = cH;
    }
}

// ---------------- K3: inter-chunk exclusive scan over chunk totals ----------------
// layout: [(h*NB+b)*NCH + c][col], 32*128 = 4096 independent chains of length 64
__global__ __launch_bounds__(256)
void k3_tops(const float* __restrict__ Atop, const float* __restrict__ Htop,
             float* __restrict__ Hst)
{
    const int idx = blockIdx.x * 256 + threadIdx.x;   // over 32*128
    const int col = idx & 127;
    const int hb  = idx >> 7;
    const size_t base = (size_t)hb * NCH * 128 + col;
    float hh = 0.f;
    #pragma unroll 16
    for (int cc = 0; cc < NCH; ++cc) {
        const size_t o = base + (size_t)cc * 128;
        Hst[o] = hh;                 // exclusive: state entering chunk cc
        hh = fmaf(Atop[o], hh, Htop[o]);
    }
}

extern "C" void kernel_launch(void* const* d_in, const int* in_sizes, int n_in,
                              void* d_out, int out_size, void* d_ws, size_t ws_size,
                              hipStream_t stream)
{
    (void)in_sizes; (void)n_in; (void)out_size; (void)ws_size;
    const float* x    = (const float*)d_in[0];
    const int*   seg  = (const int*)  d_in[1];
    const float* ap   = (const float*)d_in[2];
    const float* w_in = (const float*)d_in[3];
    const float* b_in = (const float*)d_in[4];
    const float* w_a  = (const float*)d_in[5];
    const float* b_a  = (const float*)d_in[6];
    float* out = (float*)d_out;

    // ws layout (~3.5 MiB): Atop/Htop/Hst (1 MiB each) + wfH (0.5 MiB)
    const size_t NTOP = (size_t)NH * NB * NCH * 128;
    float* Atop = (float*)d_ws;
    float* Htop = Atop + NTOP;
    float* Hst  = Htop + NTOP;
    short* wfH  = (short*)(Hst + NTOP);

    k0_wfrag<<<256, 256, 0, stream>>>(w_in, w_a, wfH);
    dim3 g1(NH, NB * NCH);
    k_pass<<<g1, 512, 0, stream>>>(x, seg, ap, b_in, b_a, wfH, Hst,
                                   Atop, Htop, out, 0);
    k3_tops<<<(NH * NB * 128) / 256, 256, 0, stream>>>(Atop, Htop, Hst);
    k_pass<<<g1, 512, 0, stream>>>(x, seg, ap, b_in, b_a, wfH, Hst,
                                   Atop, Htop, out, 1);
}